// Round 14
// baseline (266.889 us; speedup 1.0000x reference)
//
#include <hip/hip_runtime.h>

// Transformer-XL relative multi-head attention + LayerNorm.
// Inputs/outputs fp32; internal MFMA compute in bf16.
// B=2, H=16, D=64, E=1024, QL=1024, ML=1024, KLEN=2048.
// rel_shift identity: unmasked (j<=i+ML): BDshift[i,j] = BD[i, j-i+QL-1].
// R14: single change vs R13 — attn_k's V tile no longer staged in LDS.
// B-operand V fragments are contiguous 16B slices of Vt[b][h][d][j], so
// they load straight global->register (issued at loop top, consumed after
// ~26 MFMAs). Removes Vs (16 KB): LDS 67->51 KB => 3 blocks/CU (occupancy
// cap 17->25%). Same HBM bytes. proj_k/gemm_o/ln_k/pre_k byte-identical.

typedef __bf16 bf16;
typedef __bf16 bf16x4 __attribute__((ext_vector_type(4)));
typedef __bf16 bf16x8 __attribute__((ext_vector_type(8)));
typedef float f32x4 __attribute__((ext_vector_type(4)));

#define MFMA16(a, b, c) __builtin_amdgcn_mfma_f32_16x16x32_bf16((a), (b), (c), 0, 0, 0)

constexpr int E = 1024;
constexpr int NH = 16;
constexpr int DH = 64;
constexpr int QL = 1024;
constexpr int ML = 1024;
constexpr int KLEN = 2048;

// async 16B global->LDS. LDS dest is wave-uniform base + lane*16.
__device__ __forceinline__ void ldg2lds16(const bf16* g, bf16* l) {
    __builtin_amdgcn_global_load_lds(
        (const __attribute__((address_space(1))) unsigned int*)g,
        (__attribute__((address_space(3))) unsigned int*)l, 16, 0, 0);
}

// read a b128 fragment from an unpadded 64-col swizzled tile.
// physical 16B-chunk = logical chunk ^ (row & 7).
__device__ __forceinline__ bf16x8 frag8(const bf16* t, int row, int ch) {
    return *(const bf16x8*)(t + row * 64 + ((ch ^ (row & 7)) << 3));
}

// ---------------------------------------------------------------- pre
// blocks 0..5119: 5 weight transposes (WT[n][k] = bf16(W[k][n]))
// blocks 5120..9215: cat[b][jj][e] = bf16(concat(member, w))
__global__ void pre_k(const float* __restrict__ Wq, const float* __restrict__ Wk,
                      const float* __restrict__ Wv, const float* __restrict__ Wr,
                      const float* __restrict__ Wo, const float* __restrict__ member,
                      const float* __restrict__ w, bf16* __restrict__ WqT,
                      bf16* __restrict__ WkT, bf16* __restrict__ WvT,
                      bf16* __restrict__ WrT, bf16* __restrict__ WoT,
                      bf16* __restrict__ cat) {
    const int id = blockIdx.x;
    const int tid = threadIdx.x;
    __shared__ float t[32][33];
    if (id < 5120) {
        const float* W; bf16* WT;
        switch (id >> 10) {
            case 0: W = Wq; WT = WqT; break;
            case 1: W = Wk; WT = WkT; break;
            case 2: W = Wv; WT = WvT; break;
            case 3: W = Wr; WT = WrT; break;
            default: W = Wo; WT = WoT; break;
        }
        int xy = id & 1023;
        int bx = (xy & 31) * 32, by = (xy >> 5) * 32;
        int x = tid & 31, y = tid >> 5;
        for (int yy = y; yy < 32; yy += 8)
            t[yy][x] = W[(by + yy) * E + bx + x];
        __syncthreads();
        for (int yy = y; yy < 32; yy += 8)
            WT[(bx + yy) * E + by + x] = (bf16)t[x][yy];
    } else {
        int row = id - 5120;
        int b = row >> 11, jj = row & 2047;
        const float* src = (jj < ML) ? member + ((size_t)(b * ML + jj)) * E
                                     : w + ((size_t)(b * QL + (jj - ML))) * E;
        float4 f = *(const float4*)(src + tid * 4);
        bf16x4 o;
        o[0] = (bf16)f.x; o[1] = (bf16)f.y; o[2] = (bf16)f.z; o[3] = (bf16)f.w;
        *(bf16x4*)(cat + (size_t)row * E + tid * 4) = o;
    }
}

// ---------------------------------------------------------------- projections
// EXACT R9 body. Single-buffer two-barrier staging.
// zone 0: Q (+biases, *1/32 folded -> Qw/Qr [b][h][i][d])
// zone 1: K -> Kh [b][h][j][d];  zone 2: V -> Vt [b][h][d][j];  zone 3: R -> RRh
__global__ __launch_bounds__(256) void proj_k(
    const bf16* __restrict__ cat, const float* __restrict__ r,
    const bf16* __restrict__ WqT, const bf16* __restrict__ WkT,
    const bf16* __restrict__ WvT, const bf16* __restrict__ WrT,
    const float* __restrict__ rwb, const float* __restrict__ rrb,
    bf16* __restrict__ Qw, bf16* __restrict__ Qr, bf16* __restrict__ Kh,
    bf16* __restrict__ Vt, bf16* __restrict__ RRh) {
    __shared__ __align__(16) bf16 As[128 * 64];
    __shared__ __align__(16) bf16 Bs[128 * 64];
    const int tid = threadIdx.x;
    const int wave = tid >> 6, lane = tid & 63, quad = lane >> 4, l16 = lane & 15;

    int id = blockIdx.x, zone, base;
    if (id < 128) { zone = 0; base = 0; }
    else if (id < 384) { zone = 1; base = 128; }
    else if (id < 640) { zone = 2; base = 384; }
    else { zone = 3; base = 640; }
    const int lid = id - base;
    const int bn = (lid & 7) * 128, bm = (lid >> 3) * 128;
    const bf16* Bt = (zone == 0) ? WqT : (zone == 1) ? WkT : (zone == 2) ? WvT : WrT;
    const int wm = (wave >> 1) * 64, wn = (wave & 1) * 64;

    f32x4 acc[4][4] = {};

    for (int kk = 0; kk < E; kk += 64) {
        if (zone == 3) {  // fp32 A: manual convert+write (swizzled slots)
            int srw = tid >> 3, cch = tid & 7;
            for (int c = 0; c < 4; ++c) {
                int row = c * 32 + srw;
                const float* ap = r + (size_t)(bm + row) * E + kk + cch * 8;
                float4 f0 = *(const float4*)ap;
                float4 f1 = *(const float4*)(ap + 4);
                bf16x8 v;
                v[0] = (bf16)f0.x; v[1] = (bf16)f0.y; v[2] = (bf16)f0.z; v[3] = (bf16)f0.w;
                v[4] = (bf16)f1.x; v[5] = (bf16)f1.y; v[6] = (bf16)f1.z; v[7] = (bf16)f1.w;
                *(bf16x8*)(As + row * 64 + ((cch ^ (row & 7)) << 3)) = v;
            }
        } else {
            for (int issue = 0; issue < 4; ++issue) {
                int q = (issue * 4 + wave) * 64 + lane;
                int row = q >> 3, cs = (q & 7) ^ ((q >> 3) & 7);
                int gm = bm + row;
                const bf16* ap;
                if (zone == 0) {
                    int b = gm >> 10;
                    ap = cat + ((size_t)(b * 2048 + 1024 + (gm & 1023))) * E;
                } else {
                    ap = cat + (size_t)gm * E;
                }
                ldg2lds16(ap + kk + cs * 8, As + (issue * 4 + wave) * 512);
            }
        }
        for (int issue = 0; issue < 4; ++issue) {
            int q = (issue * 4 + wave) * 64 + lane;
            int row = q >> 3, cs = (q & 7) ^ ((q >> 3) & 7);
            ldg2lds16(Bt + (size_t)(bn + row) * E + kk + cs * 8,
                      Bs + (issue * 4 + wave) * 512);
        }
        __syncthreads();
        for (int ks = 0; ks < 64; ks += 32) {
            bf16x8 af[4], bfr[4];
            for (int mt = 0; mt < 4; ++mt)
                af[mt] = frag8(As, wm + mt * 16 + l16, (ks >> 3) + quad);
            for (int nt = 0; nt < 4; ++nt)
                bfr[nt] = frag8(Bs, wn + nt * 16 + l16, (ks >> 3) + quad);
            for (int mt = 0; mt < 4; ++mt)
                for (int nt = 0; nt < 4; ++nt)
                    acc[mt][nt] = MFMA16(af[mt], bfr[nt], acc[mt][nt]);
        }
        __syncthreads();
    }

    if (zone == 2) {
        // Vt[b][h][d][j]: per-wave 64x64 swizzled LDS transpose, then b128 stores.
        bf16* buf = ((wave < 2) ? As : Bs) + (wave & 1) * 4096;
        for (int mt = 0; mt < 4; ++mt)
            for (int nt = 0; nt < 4; ++nt)
                for (int rr = 0; rr < 4; ++rr) {
                    int lr = mt * 16 + quad * 4 + rr;  // local j
                    int lc = nt * 16 + l16;            // local d
                    buf[lr * 64 + (((lc >> 3) ^ (lr & 7)) << 3) + (lc & 7)] =
                        (bf16)acc[mt][nt][rr];
                }
        int h = (bn + wn) >> 6;
        int gmw = bm + wm;
        int b = gmw >> 11, jb = gmw & 2047;
        for (int dp = 0; dp < 8; ++dp) {
            int dl = dp * 8 + (lane >> 3);
            int jl = (lane & 7) * 8;
            bf16x8 tmp;
            for (int jj = 0; jj < 8; ++jj) {
                int rw = jl + jj;
                tmp[jj] = buf[rw * 64 + (((dl >> 3) ^ (rw & 7)) << 3) + (dl & 7)];
            }
            *(bf16x8*)(Vt + (((size_t)(b * NH + h) * DH + dl) * KLEN) + jb + jl) = tmp;
        }
        return;
    }

    for (int mt = 0; mt < 4; ++mt)
        for (int nt = 0; nt < 4; ++nt)
            for (int rr = 0; rr < 4; ++rr) {
                int row = bm + wm + mt * 16 + quad * 4 + rr;
                int col = bn + wn + nt * 16 + l16;
                float v = acc[mt][nt][rr];
                if (zone == 0) {
                    int b = row >> 10, i = row & 1023;
                    int h = col >> 6, d = col & 63;
                    size_t o = (((size_t)(b * NH + h) * QL) + i) * DH + d;
                    Qw[o] = (bf16)((v + rwb[col]) * 0.03125f);  // fold 1/sqrt(E)
                    Qr[o] = (bf16)((v + rrb[col]) * 0.03125f);
                } else if (zone == 1) {
                    int b = row >> 11, j = row & 2047;
                    int h = col >> 6, d = col & 63;
                    Kh[(((size_t)(b * NH + h) * KLEN) + j) * DH + d] = (bf16)v;
                } else {
                    int h = col >> 6, d = col & 63;
                    RRh[(((size_t)h * KLEN) + row) * DH + d] = (bf16)v;
                }
            }
}

// ---------------------------------------------------------------- attention
// R13 structure; V fragments now loaded global->register (no Vs buffer).
// 512 blocks, 256 thr, each wave 16 q-rows. Fixed-shift softmax (M=0).
// K double-buffered via DMA; RR 3-slot rolling ring; UB holds P only.
__global__ __launch_bounds__(256) void attn_k(
    const bf16* __restrict__ Qw, const bf16* __restrict__ Qr,
    const bf16* __restrict__ Kh, const bf16* __restrict__ Vt,
    const bf16* __restrict__ RRh, bf16* __restrict__ AttO) {
    __shared__ __align__(16) bf16 Ks[2][64 * 64];
    __shared__ __align__(16) bf16 RRing[3][64 * 64];
    __shared__ __align__(16) bf16 UB[4][16 * 88];  // per-wave P (A-layout src)

    const int tid = threadIdx.x;
    const int wave = tid >> 6, lane = tid & 63, quad = lane >> 4, l16 = lane & 15;
    const int id = blockIdx.x;
    const int b = id >> 8, h = (id >> 4) & 15;
    const int qt = (id < 256) ? (id & 15) : (15 - (id & 15));
    const int i0 = qt * 64;

    const bf16* Qwb = Qw + ((size_t)(b * NH + h) * QL) * DH;
    const bf16* Qrb = Qr + ((size_t)(b * NH + h) * QL) * DH;
    const bf16* Kb = Kh + ((size_t)(b * NH + h) * KLEN) * DH;
    const bf16* Vb = Vt + ((size_t)(b * NH + h) * DH) * KLEN;  // [d][j]
    const bf16* Rb = RRh + ((size_t)h * KLEN) * DH;

    bf16x8 qw0, qw1, qr0, qr1;
    {
        int i = i0 + wave * 16 + l16;
        qw0 = *(const bf16x8*)(Qwb + (size_t)i * DH + quad * 8);
        qw1 = *(const bf16x8*)(Qwb + (size_t)i * DH + 32 + quad * 8);
        qr0 = *(const bf16x8*)(Qrb + (size_t)i * DH + quad * 8);
        qr1 = *(const bf16x8*)(Qrb + (size_t)i * DH + 32 + quad * 8);
    }

    // per-lane V fragment row base: Vb + d*KLEN (+ j0 + c*32 + quad*8 per use)
    const bf16* Vrow[4];
    for (int nt = 0; nt < 4; ++nt)
        Vrow[nt] = Vb + (size_t)(nt * 16 + l16) * KLEN + quad * 8;

    float lpart[4] = {0.f, 0.f, 0.f, 0.f};
    f32x4 oacc[4] = {};

    const int ntiles = qt + 17;
    const int cbase = 15 - qt;  // global RR chunk of window start at t=0
    const int ptbase = 3 - wave;

    auto stage_k = [&](int t) {
        const int j0 = t * 64;
        bf16* Kd = Ks[t & 1];
        for (int issue = 0; issue < 2; ++issue) {
            int q = (issue * 4 + wave) * 64 + lane;
            int row = q >> 3, cs = (q & 7) ^ ((q >> 3) & 7);
            ldg2lds16(Kb + (size_t)(j0 + row) * DH + cs * 8,
                      Kd + (issue * 4 + wave) * 512);
        }
    };
    auto stage_rr = [&](int c) {  // load global 64-row chunk c into slot c%3
        bf16* Rd = RRing[c % 3];
        for (int issue = 0; issue < 2; ++issue) {
            int q = (issue * 4 + wave) * 64 + lane;
            int row = q >> 3, cs = (q & 7) ^ ((q >> 3) & 7);
            int pr = c * 64 + row;
            pr = pr > KLEN - 1 ? KLEN - 1 : pr;  // clamped rows feed masked cols
            ldg2lds16(Rb + (size_t)pr * DH + cs * 8, Rd + (issue * 4 + wave) * 512);
        }
    };

    stage_k(0);
    stage_rr(cbase);
    stage_rr(cbase + 1);
    __syncthreads();

    for (int t = 0; t < ntiles; ++t) {
        const int j0 = t * 64;
        const bf16* Kt = Ks[t & 1];
        const bf16* Rlo = RRing[(cbase + t) % 3];
        const bf16* Rhi = RRing[(cbase + t + 1) % 3];

        // V fragments for this tile: direct global->register (contiguous 16B
        // slices of Vt; consumed after ~26 MFMAs -> latency hidden, L2-warm).
        bf16x8 vf[4][2];
        for (int nt = 0; nt < 4; ++nt) {
            vf[nt][0] = *(const bf16x8*)(Vrow[nt] + j0);
            vf[nt][1] = *(const bf16x8*)(Vrow[nt] + j0 + 32);
        }

        if (t + 1 < ntiles) {
            stage_k(t + 1);
            stage_rr(cbase + t + 2);
        }

        // BD = Qr @ RRwindow^T (this wave's 5 pt tiles) -> registers
        f32x4 bacc[5];
        for (int pi = 0; pi < 5; ++pi) {
            int pt = ptbase + pi;
            const bf16* Rsrc = (pt < 4) ? Rlo : Rhi;
            int rrow = (pt & 3) * 16 + l16;
            f32x4 a = {};
            a = MFMA16(qr0, frag8(Rsrc, rrow, quad), a);
            a = MFMA16(qr1, frag8(Rsrc, rrow, 4 + quad), a);
            bacc[pi] = a;
        }

        // AC = Qw @ K^T
        f32x4 sacc[4];
        for (int nt = 0; nt < 4; ++nt) {
            f32x4 a = {};
            a = MFMA16(qw0, frag8(Kt, nt * 16 + l16, quad), a);
            a = MFMA16(qw1, frag8(Kt, nt * 16 + l16, 4 + quad), a);
            sacc[nt] = a;
        }

        // p = exp(AC+BD); BD rel-shift gather via cross-lane shuffles:
        // dest (quad,l16,rr,nt) <- lane quad*16+((l16-lr-1)&15),
        //                          reg bacc[nt + (l16>lr)][rr].
        float sv[4][4];
        const bool lastt = (t == ntiles - 1);
        for (int rr = 0; rr < 4; ++rr) {
            const int lr = quad * 4 + rr;
            const int srcl = quad * 16 + ((l16 - lr - 1) & 15);
            float g[5];
            for (int pi = 0; pi < 5; ++pi) g[pi] = __shfl(bacc[pi][rr], srcl);
            const bool hi = (l16 > lr);
            for (int nt = 0; nt < 4; ++nt) {
                float bdv = hi ? g[nt + 1] : g[nt];
                float p = __expf(sacc[nt][rr] + bdv);
                if (lastt) {
                    int i = i0 + wave * 16 + lr;
                    int j = j0 + nt * 16 + l16;
                    if (j > i + ML) p = 0.f;
                }
                sv[nt][rr] = p;
                lpart[rr] += p;
            }
        }

        // P: C-layout -> UB -> A-layout
        for (int nt = 0; nt < 4; ++nt)
            for (int rr = 0; rr < 4; ++rr)
                UB[wave][(quad * 4 + rr) * 88 + nt * 16 + l16] = (bf16)sv[nt][rr];

        for (int c = 0; c < 2; ++c) {
            bf16x8 pa = *(const bf16x8*)(&UB[wave][l16 * 88 + c * 32 + quad * 8]);
            for (int nt = 0; nt < 4; ++nt)
                oacc[nt] = MFMA16(pa, vf[nt][c], oacc[nt]);
        }
        __syncthreads();  // prefetched t+1 complete + all reads of t done
    }

    // deferred l reduction (once, not per tile)
    float linv[4];
    for (int rr = 0; rr < 4; ++rr) {
        float v = lpart[rr];
        v += __shfl_xor(v, 1);
        v += __shfl_xor(v, 2);
        v += __shfl_xor(v, 4);
        v += __shfl_xor(v, 8);
        linv[rr] = 1.f / v;
    }

    for (int nt = 0; nt < 4; ++nt)
        for (int rr = 0; rr < 4; ++rr) {
            int i = i0 + wave * 16 + quad * 4 + rr;
            int d = nt * 16 + l16;
            AttO[((size_t)(b * QL + i)) * E + h * DH + d] =
                (bf16)(oacc[nt][rr] * linv[rr]);
        }
}

// ---------------------------------------------------------------- out proj
// split-K x2: z-half computes partial Xp[z] (fp32, no resid). ln_k sums.
// Single-buffer two-barrier staging (R9-frozen).
__global__ __launch_bounds__(256) void gemm_o(
    const bf16* __restrict__ A, const bf16* __restrict__ Bt,
    float* __restrict__ Xp) {
    __shared__ __align__(16) bf16 As[128 * 64];
    __shared__ __align__(16) bf16 Bs[128 * 64];
    const int tid = threadIdx.x;
    const int wave = tid >> 6, lane = tid & 63, quad = lane >> 4, l16 = lane & 15;
    const int bm = blockIdx.y * 128, bn = blockIdx.x * 128;
    const int kbase = blockIdx.z * 512;
    const int wm = (wave >> 1) * 64, wn = (wave & 1) * 64;

    f32x4 acc[4][4] = {};

    for (int s = 0; s < 8; ++s) {
        const int kk = kbase + s * 64;
        for (int issue = 0; issue < 4; ++issue) {
            int q = (issue * 4 + wave) * 64 + lane;
            int row = q >> 3, cs = (q & 7) ^ ((q >> 3) & 7);
            ldg2lds16(A + (size_t)(bm + row) * E + kk + cs * 8,
                      As + (issue * 4 + wave) * 512);
            ldg2lds16(Bt + (size_t)(bn + row) * E + kk + cs * 8,
                      Bs + (issue * 4 + wave) * 512);
        }
        __syncthreads();
        for (int ks = 0; ks < 64; ks += 32) {
            bf16x8 af[4], bfr[4];
            for (int mt = 0; mt < 4; ++mt)
                af[mt] = frag8(As, wm + mt * 16 + l16, (ks >> 3) + quad);
            for (int nt = 0; nt < 4; ++nt)
                bfr[nt] = frag8(Bs, wn + nt * 16 + l16, (ks >> 3) + quad);
            for (int mt = 0; mt < 4; ++mt)
                for (int nt = 0; nt < 4; ++nt)
                    acc[mt][nt] = MFMA16(af[mt], bfr[nt], acc[mt][nt]);
        }
        __syncthreads();
    }

    float* Xz = Xp + (size_t)blockIdx.z * 2048 * 1024;
    for (int mt = 0; mt < 4; ++mt)
        for (int nt = 0; nt < 4; ++nt)
            for (int rr = 0; rr < 4; ++rr) {
                int row = bm + wm + mt * 16 + quad * 4 + rr;
                int col = bn + wn + nt * 16 + l16;
                Xz[(size_t)row * E + col] = acc[mt][nt][rr];
            }
}

// ---------------------------------------------------------------- layernorm
// x = Xp0 + Xp1 + resid(w); out = LN(x)*gamma+beta
__global__ __launch_bounds__(256) void ln_k(const float* __restrict__ Xp,
                                            const float* __restrict__ resid,
                                            const float* __restrict__ gamma,
                                            const float* __restrict__ beta,
                                            float* __restrict__ out) {
    const int row = blockIdx.x;
    const int tid = threadIdx.x;
    const float* x0 = Xp + (size_t)row * E;
    const float* x1 = Xp + (size_t)2048 * 1024 + (size_t)row * E;
    const float* xr = resid + (size_t)row * E;
    float xv[4], s = 0.f, q = 0.f;
    for (int c = 0; c < 4; ++c) {
        int col = c * 256 + tid;
        float v = x0[col] + x1[col] + xr[col];
        xv[c] = v;
        s += v;
        q += v * v;
    }
    for (int off = 32; off > 0; off >>= 1) {
        s += __shfl_down(s, off);
        q += __shfl_down(q, off);
    }
    __shared__ float rs[4], rq[4];
    int wave = tid >> 6, lane = tid & 63;
    if (lane == 0) { rs[wave] = s; rq[wave] = q; }
    __syncthreads();
    float S = rs[0] + rs[1] + rs[2] + rs[3];
    float Q = rq[0] + rq[1] + rq[2] + rq[3];
    float mean = S * (1.f / E);
    float var = fmaxf(Q * (1.f / E) - mean * mean, 0.f);
    float rstd = rsqrtf(var + 1e-3f);
    for (int c = 0; c < 4; ++c) {
        int col = c * 256 + tid;
        out[(size_t)row * E + col] =
            (xv[c] - mean) * rstd * gamma[col] + beta[col];
    }
}

// ---------------------------------------------------------------- launch
extern "C" void kernel_launch(void* const* d_in, const int* in_sizes, int n_in,
                              void* d_out, int out_size, void* d_ws,
                              size_t ws_size, hipStream_t stream) {
    (void)in_sizes; (void)n_in; (void)out_size; (void)ws_size;
    const float* w = (const float*)d_in[0];
    const float* r = (const float*)d_in[1];
    const float* rwb = (const float*)d_in[3];
    const float* rrb = (const float*)d_in[4];
    const float* member = (const float*)d_in[5];
    const float* Wq = (const float*)d_in[6];
    const float* Wk = (const float*)d_in[7];
    const float* Wv = (const float*)d_in[8];
    const float* Wr = (const float*)d_in[9];
    const float* Wo = (const float*)d_in[10];
    const float* gamma = (const float*)d_in[11];
    const float* beta = (const float*)d_in[12];
    float* out = (float*)d_out;

    char* ws = (char*)d_ws;
    const size_t MB = 1024 * 1024;
    bf16* WqT = (bf16*)(ws + 0 * MB);   // 0-8: WqT/WkT/WvT/WrT (dead after proj)
    bf16* WkT = (bf16*)(ws + 2 * MB);
    bf16* WvT = (bf16*)(ws + 4 * MB);
    bf16* WrT = (bf16*)(ws + 6 * MB);
    bf16* WoT = (bf16*)(ws + 8 * MB);   // live until gemm_o
    bf16* cat = (bf16*)(ws + 10 * MB);  // 10-18; dead after proj_k
    bf16* AttO = (bf16*)(ws + 14 * MB); // 14-18 (over cat 2nd half)
    bf16* Qw = (bf16*)(ws + 18 * MB);
    bf16* Qr = (bf16*)(ws + 22 * MB);
    float* Xp = (float*)(ws + 18 * MB); // 18-34 over Qw/Qr/Kh (dead after attn)
    bf16* Kh = (bf16*)(ws + 26 * MB);
    bf16* Vt = (bf16*)(ws + 34 * MB);
    bf16* RRh = (bf16*)(ws + 42 * MB);
    // high-water: 46 MB

    pre_k<<<9216, 256, 0, stream>>>(Wq, Wk, Wv, Wr, Wo, member, w, WqT, WkT,
                                    WvT, WrT, WoT, cat);

    proj_k<<<768, 256, 0, stream>>>(cat, r, WqT, WkT, WvT, WrT, rwb, rrb, Qw,
                                    Qr, Kh, Vt, RRh);

    attn_k<<<512, 256, 0, stream>>>(Qw, Qr, Kh, Vt, RRh, AttO);

    gemm_o<<<dim3(8, 16, 2), 256, 0, stream>>>(AttO, WoT, Xp);
    ln_k<<<2048, 256, 0, stream>>>(Xp, w, gamma, beta, out);
}

// Round 15
// 258.411 us; speedup vs baseline: 1.0328x; 1.0328x over previous
//
#include <hip/hip_runtime.h>

// Transformer-XL relative multi-head attention + LayerNorm.
// Inputs/outputs fp32; internal MFMA compute in bf16.
// B=2, H=16, D=64, E=1024, QL=1024, ML=1024, KLEN=2048.
// rel_shift identity: unmasked (j<=i+ML): BDshift[i,j] = BD[i, j-i+QL-1].
// R15: REVERT to R13 (best: 259.6 us). R14's V-direct-load regressed
// (83.7 vs 74.0 us: LDS granularity kept occupancy at ~2 blocks/CU while
// V latency moved onto the critical path). R13 = final configuration:
// - attn_k: fixed-shift softmax, K DMA dbuf, RR ring, BD shuffle-gather.
// - proj_k/gemm_o: R9 two-barrier global_load_lds staging (frozen).
// - pre_k merged; gemm_o split-K x2 + ln-fused residual.

typedef __bf16 bf16;
typedef __bf16 bf16x4 __attribute__((ext_vector_type(4)));
typedef __bf16 bf16x8 __attribute__((ext_vector_type(8)));
typedef float f32x4 __attribute__((ext_vector_type(4)));

#define MFMA16(a, b, c) __builtin_amdgcn_mfma_f32_16x16x32_bf16((a), (b), (c), 0, 0, 0)

constexpr int E = 1024;
constexpr int NH = 16;
constexpr int DH = 64;
constexpr int QL = 1024;
constexpr int ML = 1024;
constexpr int KLEN = 2048;

// async 16B global->LDS. LDS dest is wave-uniform base + lane*16.
__device__ __forceinline__ void ldg2lds16(const bf16* g, bf16* l) {
    __builtin_amdgcn_global_load_lds(
        (const __attribute__((address_space(1))) unsigned int*)g,
        (__attribute__((address_space(3))) unsigned int*)l, 16, 0, 0);
}

// read a b128 fragment from an unpadded 64-col swizzled tile.
// physical 16B-chunk = logical chunk ^ (row & 7).
__device__ __forceinline__ bf16x8 frag8(const bf16* t, int row, int ch) {
    return *(const bf16x8*)(t + row * 64 + ((ch ^ (row & 7)) << 3));
}

// ---------------------------------------------------------------- pre
// blocks 0..5119: 5 weight transposes (WT[n][k] = bf16(W[k][n]))
// blocks 5120..9215: cat[b][jj][e] = bf16(concat(member, w))
__global__ void pre_k(const float* __restrict__ Wq, const float* __restrict__ Wk,
                      const float* __restrict__ Wv, const float* __restrict__ Wr,
                      const float* __restrict__ Wo, const float* __restrict__ member,
                      const float* __restrict__ w, bf16* __restrict__ WqT,
                      bf16* __restrict__ WkT, bf16* __restrict__ WvT,
                      bf16* __restrict__ WrT, bf16* __restrict__ WoT,
                      bf16* __restrict__ cat) {
    const int id = blockIdx.x;
    const int tid = threadIdx.x;
    __shared__ float t[32][33];
    if (id < 5120) {
        const float* W; bf16* WT;
        switch (id >> 10) {
            case 0: W = Wq; WT = WqT; break;
            case 1: W = Wk; WT = WkT; break;
            case 2: W = Wv; WT = WvT; break;
            case 3: W = Wr; WT = WrT; break;
            default: W = Wo; WT = WoT; break;
        }
        int xy = id & 1023;
        int bx = (xy & 31) * 32, by = (xy >> 5) * 32;
        int x = tid & 31, y = tid >> 5;
        for (int yy = y; yy < 32; yy += 8)
            t[yy][x] = W[(by + yy) * E + bx + x];
        __syncthreads();
        for (int yy = y; yy < 32; yy += 8)
            WT[(bx + yy) * E + by + x] = (bf16)t[x][yy];
    } else {
        int row = id - 5120;
        int b = row >> 11, jj = row & 2047;
        const float* src = (jj < ML) ? member + ((size_t)(b * ML + jj)) * E
                                     : w + ((size_t)(b * QL + (jj - ML))) * E;
        float4 f = *(const float4*)(src + tid * 4);
        bf16x4 o;
        o[0] = (bf16)f.x; o[1] = (bf16)f.y; o[2] = (bf16)f.z; o[3] = (bf16)f.w;
        *(bf16x4*)(cat + (size_t)row * E + tid * 4) = o;
    }
}

// ---------------------------------------------------------------- projections
// EXACT R9 body. Single-buffer two-barrier staging.
// zone 0: Q (+biases, *1/32 folded -> Qw/Qr [b][h][i][d])
// zone 1: K -> Kh [b][h][j][d];  zone 2: V -> Vt [b][h][d][j];  zone 3: R -> RRh
__global__ __launch_bounds__(256) void proj_k(
    const bf16* __restrict__ cat, const float* __restrict__ r,
    const bf16* __restrict__ WqT, const bf16* __restrict__ WkT,
    const bf16* __restrict__ WvT, const bf16* __restrict__ WrT,
    const float* __restrict__ rwb, const float* __restrict__ rrb,
    bf16* __restrict__ Qw, bf16* __restrict__ Qr, bf16* __restrict__ Kh,
    bf16* __restrict__ Vt, bf16* __restrict__ RRh) {
    __shared__ __align__(16) bf16 As[128 * 64];
    __shared__ __align__(16) bf16 Bs[128 * 64];
    const int tid = threadIdx.x;
    const int wave = tid >> 6, lane = tid & 63, quad = lane >> 4, l16 = lane & 15;

    int id = blockIdx.x, zone, base;
    if (id < 128) { zone = 0; base = 0; }
    else if (id < 384) { zone = 1; base = 128; }
    else if (id < 640) { zone = 2; base = 384; }
    else { zone = 3; base = 640; }
    const int lid = id - base;
    const int bn = (lid & 7) * 128, bm = (lid >> 3) * 128;
    const bf16* Bt = (zone == 0) ? WqT : (zone == 1) ? WkT : (zone == 2) ? WvT : WrT;
    const int wm = (wave >> 1) * 64, wn = (wave & 1) * 64;

    f32x4 acc[4][4] = {};

    for (int kk = 0; kk < E; kk += 64) {
        if (zone == 3) {  // fp32 A: manual convert+write (swizzled slots)
            int srw = tid >> 3, cch = tid & 7;
            for (int c = 0; c < 4; ++c) {
                int row = c * 32 + srw;
                const float* ap = r + (size_t)(bm + row) * E + kk + cch * 8;
                float4 f0 = *(const float4*)ap;
                float4 f1 = *(const float4*)(ap + 4);
                bf16x8 v;
                v[0] = (bf16)f0.x; v[1] = (bf16)f0.y; v[2] = (bf16)f0.z; v[3] = (bf16)f0.w;
                v[4] = (bf16)f1.x; v[5] = (bf16)f1.y; v[6] = (bf16)f1.z; v[7] = (bf16)f1.w;
                *(bf16x8*)(As + row * 64 + ((cch ^ (row & 7)) << 3)) = v;
            }
        } else {
            for (int issue = 0; issue < 4; ++issue) {
                int q = (issue * 4 + wave) * 64 + lane;
                int row = q >> 3, cs = (q & 7) ^ ((q >> 3) & 7);
                int gm = bm + row;
                const bf16* ap;
                if (zone == 0) {
                    int b = gm >> 10;
                    ap = cat + ((size_t)(b * 2048 + 1024 + (gm & 1023))) * E;
                } else {
                    ap = cat + (size_t)gm * E;
                }
                ldg2lds16(ap + kk + cs * 8, As + (issue * 4 + wave) * 512);
            }
        }
        for (int issue = 0; issue < 4; ++issue) {
            int q = (issue * 4 + wave) * 64 + lane;
            int row = q >> 3, cs = (q & 7) ^ ((q >> 3) & 7);
            ldg2lds16(Bt + (size_t)(bn + row) * E + kk + cs * 8,
                      Bs + (issue * 4 + wave) * 512);
        }
        __syncthreads();
        for (int ks = 0; ks < 64; ks += 32) {
            bf16x8 af[4], bfr[4];
            for (int mt = 0; mt < 4; ++mt)
                af[mt] = frag8(As, wm + mt * 16 + l16, (ks >> 3) + quad);
            for (int nt = 0; nt < 4; ++nt)
                bfr[nt] = frag8(Bs, wn + nt * 16 + l16, (ks >> 3) + quad);
            for (int mt = 0; mt < 4; ++mt)
                for (int nt = 0; nt < 4; ++nt)
                    acc[mt][nt] = MFMA16(af[mt], bfr[nt], acc[mt][nt]);
        }
        __syncthreads();
    }

    if (zone == 2) {
        // Vt[b][h][d][j]: per-wave 64x64 swizzled LDS transpose, then b128 stores.
        bf16* buf = ((wave < 2) ? As : Bs) + (wave & 1) * 4096;
        for (int mt = 0; mt < 4; ++mt)
            for (int nt = 0; nt < 4; ++nt)
                for (int rr = 0; rr < 4; ++rr) {
                    int lr = mt * 16 + quad * 4 + rr;  // local j
                    int lc = nt * 16 + l16;            // local d
                    buf[lr * 64 + (((lc >> 3) ^ (lr & 7)) << 3) + (lc & 7)] =
                        (bf16)acc[mt][nt][rr];
                }
        int h = (bn + wn) >> 6;
        int gmw = bm + wm;
        int b = gmw >> 11, jb = gmw & 2047;
        for (int dp = 0; dp < 8; ++dp) {
            int dl = dp * 8 + (lane >> 3);
            int jl = (lane & 7) * 8;
            bf16x8 tmp;
            for (int jj = 0; jj < 8; ++jj) {
                int rw = jl + jj;
                tmp[jj] = buf[rw * 64 + (((dl >> 3) ^ (rw & 7)) << 3) + (dl & 7)];
            }
            *(bf16x8*)(Vt + (((size_t)(b * NH + h) * DH + dl) * KLEN) + jb + jl) = tmp;
        }
        return;
    }

    for (int mt = 0; mt < 4; ++mt)
        for (int nt = 0; nt < 4; ++nt)
            for (int rr = 0; rr < 4; ++rr) {
                int row = bm + wm + mt * 16 + quad * 4 + rr;
                int col = bn + wn + nt * 16 + l16;
                float v = acc[mt][nt][rr];
                if (zone == 0) {
                    int b = row >> 10, i = row & 1023;
                    int h = col >> 6, d = col & 63;
                    size_t o = (((size_t)(b * NH + h) * QL) + i) * DH + d;
                    Qw[o] = (bf16)((v + rwb[col]) * 0.03125f);  // fold 1/sqrt(E)
                    Qr[o] = (bf16)((v + rrb[col]) * 0.03125f);
                } else if (zone == 1) {
                    int b = row >> 11, j = row & 2047;
                    int h = col >> 6, d = col & 63;
                    Kh[(((size_t)(b * NH + h) * KLEN) + j) * DH + d] = (bf16)v;
                } else {
                    int h = col >> 6, d = col & 63;
                    RRh[(((size_t)h * KLEN) + row) * DH + d] = (bf16)v;
                }
            }
}

// ---------------------------------------------------------------- attention
// R5/R9 structure; BD gather in-register via cross-lane shuffles (R13).
// 512 blocks, 256 thr, each wave 16 q-rows. Fixed-shift softmax (M=0).
// K/V double-buffered; RR 3-slot rolling ring; UB holds P only.
__global__ __launch_bounds__(256) void attn_k(
    const bf16* __restrict__ Qw, const bf16* __restrict__ Qr,
    const bf16* __restrict__ Kh, const bf16* __restrict__ Vt,
    const bf16* __restrict__ RRh, bf16* __restrict__ AttO) {
    __shared__ __align__(16) bf16 Ks[2][64 * 64];
    __shared__ __align__(16) bf16 Vs[2][64 * 64];
    __shared__ __align__(16) bf16 RRing[3][64 * 64];
    __shared__ __align__(16) bf16 UB[4][16 * 88];  // per-wave P (A-layout src)

    const int tid = threadIdx.x;
    const int wave = tid >> 6, lane = tid & 63, quad = lane >> 4, l16 = lane & 15;
    const int id = blockIdx.x;
    const int b = id >> 8, h = (id >> 4) & 15;
    const int qt = (id < 256) ? (id & 15) : (15 - (id & 15));
    const int i0 = qt * 64;

    const bf16* Qwb = Qw + ((size_t)(b * NH + h) * QL) * DH;
    const bf16* Qrb = Qr + ((size_t)(b * NH + h) * QL) * DH;
    const bf16* Kb = Kh + ((size_t)(b * NH + h) * KLEN) * DH;
    const bf16* Vb = Vt + ((size_t)(b * NH + h) * DH) * KLEN;  // [d][j]
    const bf16* Rb = RRh + ((size_t)h * KLEN) * DH;

    bf16x8 qw0, qw1, qr0, qr1;
    {
        int i = i0 + wave * 16 + l16;
        qw0 = *(const bf16x8*)(Qwb + (size_t)i * DH + quad * 8);
        qw1 = *(const bf16x8*)(Qwb + (size_t)i * DH + 32 + quad * 8);
        qr0 = *(const bf16x8*)(Qrb + (size_t)i * DH + quad * 8);
        qr1 = *(const bf16x8*)(Qrb + (size_t)i * DH + 32 + quad * 8);
    }

    float lpart[4] = {0.f, 0.f, 0.f, 0.f};
    f32x4 oacc[4] = {};

    const int ntiles = qt + 17;
    const int cbase = 15 - qt;  // global RR chunk of window start at t=0
    const int ptbase = 3 - wave;

    auto stage_kv = [&](int t) {
        const int j0 = t * 64;
        bf16* Kd = Ks[t & 1];
        bf16* Vd = Vs[t & 1];
        for (int issue = 0; issue < 2; ++issue) {
            int q = (issue * 4 + wave) * 64 + lane;
            int row = q >> 3, cs = (q & 7) ^ ((q >> 3) & 7);
            ldg2lds16(Kb + (size_t)(j0 + row) * DH + cs * 8,
                      Kd + (issue * 4 + wave) * 512);
            ldg2lds16(Vb + (size_t)row * KLEN + j0 + cs * 8,
                      Vd + (issue * 4 + wave) * 512);
        }
    };
    auto stage_rr = [&](int c) {  // load global 64-row chunk c into slot c%3
        bf16* Rd = RRing[c % 3];
        for (int issue = 0; issue < 2; ++issue) {
            int q = (issue * 4 + wave) * 64 + lane;
            int row = q >> 3, cs = (q & 7) ^ ((q >> 3) & 7);
            int pr = c * 64 + row;
            pr = pr > KLEN - 1 ? KLEN - 1 : pr;  // clamped rows feed masked cols
            ldg2lds16(Rb + (size_t)pr * DH + cs * 8, Rd + (issue * 4 + wave) * 512);
        }
    };

    stage_kv(0);
    stage_rr(cbase);
    stage_rr(cbase + 1);
    __syncthreads();

    for (int t = 0; t < ntiles; ++t) {
        const bf16* Kt = Ks[t & 1];
        const bf16* Vl = Vs[t & 1];
        const bf16* Rlo = RRing[(cbase + t) % 3];
        const bf16* Rhi = RRing[(cbase + t + 1) % 3];
        if (t + 1 < ntiles) {
            stage_kv(t + 1);
            stage_rr(cbase + t + 2);
        }

        // BD = Qr @ RRwindow^T (this wave's 5 pt tiles) -> registers
        f32x4 bacc[5];
        for (int pi = 0; pi < 5; ++pi) {
            int pt = ptbase + pi;
            const bf16* Rsrc = (pt < 4) ? Rlo : Rhi;
            int rrow = (pt & 3) * 16 + l16;
            f32x4 a = {};
            a = MFMA16(qr0, frag8(Rsrc, rrow, quad), a);
            a = MFMA16(qr1, frag8(Rsrc, rrow, 4 + quad), a);
            bacc[pi] = a;
        }

        // AC = Qw @ K^T
        f32x4 sacc[4];
        for (int nt = 0; nt < 4; ++nt) {
            f32x4 a = {};
            a = MFMA16(qw0, frag8(Kt, nt * 16 + l16, quad), a);
            a = MFMA16(qw1, frag8(Kt, nt * 16 + l16, 4 + quad), a);
            sacc[nt] = a;
        }

        // p = exp(AC+BD); BD rel-shift gather via cross-lane shuffles:
        // dest (quad,l16,rr,nt) <- lane quad*16+((l16-lr-1)&15),
        //                          reg bacc[nt + (l16>lr)][rr].
        float sv[4][4];
        const bool lastt = (t == ntiles - 1);
        for (int rr = 0; rr < 4; ++rr) {
            const int lr = quad * 4 + rr;
            const int srcl = quad * 16 + ((l16 - lr - 1) & 15);
            float g[5];
            for (int pi = 0; pi < 5; ++pi) g[pi] = __shfl(bacc[pi][rr], srcl);
            const bool hi = (l16 > lr);
            for (int nt = 0; nt < 4; ++nt) {
                float bdv = hi ? g[nt + 1] : g[nt];
                float p = __expf(sacc[nt][rr] + bdv);
                if (lastt) {
                    int i = i0 + wave * 16 + lr;
                    int j = t * 64 + nt * 16 + l16;
                    if (j > i + ML) p = 0.f;
                }
                sv[nt][rr] = p;
                lpart[rr] += p;
            }
        }

        // P: C-layout -> UB -> A-layout
        for (int nt = 0; nt < 4; ++nt)
            for (int rr = 0; rr < 4; ++rr)
                UB[wave][(quad * 4 + rr) * 88 + nt * 16 + l16] = (bf16)sv[nt][rr];

        for (int c = 0; c < 2; ++c) {
            bf16x8 pa = *(const bf16x8*)(&UB[wave][l16 * 88 + c * 32 + quad * 8]);
            for (int nt = 0; nt < 4; ++nt) {
                bf16x8 vb = frag8(Vl, nt * 16 + l16, c * 4 + quad);
                oacc[nt] = MFMA16(pa, vb, oacc[nt]);
            }
        }
        __syncthreads();  // prefetched t+1 complete + all reads of t done
    }

    // deferred l reduction (once, not per tile)
    float linv[4];
    for (int rr = 0; rr < 4; ++rr) {
        float v = lpart[rr];
        v += __shfl_xor(v, 1);
        v += __shfl_xor(v, 2);
        v += __shfl_xor(v, 4);
        v += __shfl_xor(v, 8);
        linv[rr] = 1.f / v;
    }

    for (int nt = 0; nt < 4; ++nt)
        for (int rr = 0; rr < 4; ++rr) {
            int i = i0 + wave * 16 + quad * 4 + rr;
            int d = nt * 16 + l16;
            AttO[((size_t)(b * QL + i)) * E + h * DH + d] =
                (bf16)(oacc[nt][rr] * linv[rr]);
        }
}

// ---------------------------------------------------------------- out proj
// split-K x2: z-half computes partial Xp[z] (fp32, no resid). ln_k sums.
// Single-buffer two-barrier staging (R9-frozen).
__global__ __launch_bounds__(256) void gemm_o(
    const bf16* __restrict__ A, const bf16* __restrict__ Bt,
    float* __restrict__ Xp) {
    __shared__ __align__(16) bf16 As[128 * 64];
    __shared__ __align__(16) bf16 Bs[128 * 64];
    const int tid = threadIdx.x;
    const int wave = tid >> 6, lane = tid & 63, quad = lane >> 4, l16 = lane & 15;
    const int bm = blockIdx.y * 128, bn = blockIdx.x * 128;
    const int kbase = blockIdx.z * 512;
    const int wm = (wave >> 1) * 64, wn = (wave & 1) * 64;

    f32x4 acc[4][4] = {};

    for (int s = 0; s < 8; ++s) {
        const int kk = kbase + s * 64;
        for (int issue = 0; issue < 4; ++issue) {
            int q = (issue * 4 + wave) * 64 + lane;
            int row = q >> 3, cs = (q & 7) ^ ((q >> 3) & 7);
            ldg2lds16(A + (size_t)(bm + row) * E + kk + cs * 8,
                      As + (issue * 4 + wave) * 512);
            ldg2lds16(Bt + (size_t)(bn + row) * E + kk + cs * 8,
                      Bs + (issue * 4 + wave) * 512);
        }
        __syncthreads();
        for (int ks = 0; ks < 64; ks += 32) {
            bf16x8 af[4], bfr[4];
            for (int mt = 0; mt < 4; ++mt)
                af[mt] = frag8(As, wm + mt * 16 + l16, (ks >> 3) + quad);
            for (int nt = 0; nt < 4; ++nt)
                bfr[nt] = frag8(Bs, wn + nt * 16 + l16, (ks >> 3) + quad);
            for (int mt = 0; mt < 4; ++mt)
                for (int nt = 0; nt < 4; ++nt)
                    acc[mt][nt] = MFMA16(af[mt], bfr[nt], acc[mt][nt]);
        }
        __syncthreads();
    }

    float* Xz = Xp + (size_t)blockIdx.z * 2048 * 1024;
    for (int mt = 0; mt < 4; ++mt)
        for (int nt = 0; nt < 4; ++nt)
            for (int rr = 0; rr < 4; ++rr) {
                int row = bm + wm + mt * 16 + quad * 4 + rr;
                int col = bn + wn + nt * 16 + l16;
                Xz[(size_t)row * E + col] = acc[mt][nt][rr];
            }
}

// ---------------------------------------------------------------- layernorm
// x = Xp0 + Xp1 + resid(w); out = LN(x)*gamma+beta
__global__ __launch_bounds__(256) void ln_k(const float* __restrict__ Xp,
                                            const float* __restrict__ resid,
                                            const float* __restrict__ gamma,
                                            const float* __restrict__ beta,
                                            float* __restrict__ out) {
    const int row = blockIdx.x;
    const int tid = threadIdx.x;
    const float* x0 = Xp + (size_t)row * E;
    const float* x1 = Xp + (size_t)2048 * 1024 + (size_t)row * E;
    const float* xr = resid + (size_t)row * E;
    float xv[4], s = 0.f, q = 0.f;
    for (int c = 0; c < 4; ++c) {
        int col = c * 256 + tid;
        float v = x0[col] + x1[col] + xr[col];
        xv[c] = v;
        s += v;
        q += v * v;
    }
    for (int off = 32; off > 0; off >>= 1) {
        s += __shfl_down(s, off);
        q += __shfl_down(q, off);
    }
    __shared__ float rs[4], rq[4];
    int wave = tid >> 6, lane = tid & 63;
    if (lane == 0) { rs[wave] = s; rq[wave] = q; }
    __syncthreads();
    float S = rs[0] + rs[1] + rs[2] + rs[3];
    float Q = rq[0] + rq[1] + rq[2] + rq[3];
    float mean = S * (1.f / E);
    float var = fmaxf(Q * (1.f / E) - mean * mean, 0.f);
    float rstd = rsqrtf(var + 1e-3f);
    for (int c = 0; c < 4; ++c) {
        int col = c * 256 + tid;
        out[(size_t)row * E + col] =
            (xv[c] - mean) * rstd * gamma[col] + beta[col];
    }
}

// ---------------------------------------------------------------- launch
extern "C" void kernel_launch(void* const* d_in, const int* in_sizes, int n_in,
                              void* d_out, int out_size, void* d_ws,
                              size_t ws_size, hipStream_t stream) {
    (void)in_sizes; (void)n_in; (void)out_size; (void)ws_size;
    const float* w = (const float*)d_in[0];
    const float* r = (const float*)d_in[1];
    const float* rwb = (const float*)d_in[3];
    const float* rrb = (const float*)d_in[4];
    const float* member = (const float*)d_in[5];
    const float* Wq = (const float*)d_in[6];
    const float* Wk = (const float*)d_in[7];
    const float* Wv = (const float*)d_in[8];
    const float* Wr = (const float*)d_in[9];
    const float* Wo = (const float*)d_in[10];
    const float* gamma = (const float*)d_in[11];
    const float* beta = (const float*)d_in[12];
    float* out = (float*)d_out;

    char* ws = (char*)d_ws;
    const size_t MB = 1024 * 1024;
    bf16* WqT = (bf16*)(ws + 0 * MB);   // 0-8: WqT/WkT/WvT/WrT (dead after proj)
    bf16* WkT = (bf16*)(ws + 2 * MB);
    bf16* WvT = (bf16*)(ws + 4 * MB);
    bf16* WrT = (bf16*)(ws + 6 * MB);
    bf16* WoT = (bf16*)(ws + 8 * MB);   // live until gemm_o
    bf16* cat = (bf16*)(ws + 10 * MB);  // 10-18; dead after proj_k
    bf16* AttO = (bf16*)(ws + 14 * MB); // 14-18 (over cat 2nd half)
    bf16* Qw = (bf16*)(ws + 18 * MB);
    bf16* Qr = (bf16*)(ws + 22 * MB);
    float* Xp = (float*)(ws + 18 * MB); // 18-34 over Qw/Qr/Kh (dead after attn)
    bf16* Kh = (bf16*)(ws + 26 * MB);
    bf16* Vt = (bf16*)(ws + 34 * MB);
    bf16* RRh = (bf16*)(ws + 42 * MB);
    // high-water: 46 MB

    pre_k<<<9216, 256, 0, stream>>>(Wq, Wk, Wv, Wr, Wo, member, w, WqT, WkT,
                                    WvT, WrT, WoT, cat);

    proj_k<<<768, 256, 0, stream>>>(cat, r, WqT, WkT, WvT, WrT, rwb, rrb, Qw,
                                    Qr, Kh, Vt, RRh);

    attn_k<<<512, 256, 0, stream>>>(Qw, Qr, Kh, Vt, RRh, AttO);

    gemm_o<<<dim3(8, 16, 2), 256, 0, stream>>>(AttO, WoT, Xp);
    ln_k<<<2048, 256, 0, stream>>>(Xp, w, gamma, beta, out);
}